// Round 8
// baseline (8965.696 us; speedup 1.0000x reference)
//
#include <hip/hip_runtime.h>
#include <hip/hip_cooperative_groups.h>

namespace cg = cooperative_groups;

// BalRNN: B=32, T=64, IN=512, L=2, H=4096, K=64
// ws layout (floats):
//   xe    [T][H][B]   offset 0            (8,388,608)
//   h0    [2][H][B]   offset 8,388,608    (262,144)  double-buffered h0 state
//   hsum  [3][H][B]   offset 8,650,752    (393,216)  h0(t)+h1(t-1) accumulator
// state layout [h][b]: one gathered row = 128B contiguous, 128B-aligned.
// h_final is written REGISTER-DIRECT inside the scan (no buffer round-trip):
//   layer 0 by A-role at t=63, layer 1 by B-role at t=64.

constexpr int B_ = 32, T_ = 64, IN_ = 512, H_ = 4096, K_ = 64;
constexpr int HB_ = H_ * B_;            // 131072
constexpr int XE_ELEMS = T_ * HB_;      // 8388608
constexpr int NBLK = 1024, NTHR = 256;
constexpr int OFF0 = B_ * T_ * H_;      // h_final layer-0 region in d_out
constexpr int OFF1 = OFF0 + B_ * H_;    // h_final layer-1 region in d_out

// ---------------------------------------------------------------------------
// xe[t][h][b] = sum_i w[h][i] * x[b][t][i]   (measured R1: 131 us)
// ---------------------------------------------------------------------------
__global__ __launch_bounds__(256) void gemm_xe(const float* __restrict__ x,
                                               const float* __restrict__ w,
                                               float* __restrict__ xe) {
    __shared__ float As[16][64];
    __shared__ float Bs[16][64];
    const int tid = threadIdx.x;
    const int m0 = blockIdx.x * 64;
    const int n0 = blockIdx.y * 64;
    const int row = tid >> 2;
    const int kq  = tid & 3;

    const float* aSrc = w + (m0 + row) * IN_ + kq * 4;
    const int n = n0 + row;
    const float* bSrc = x + (n & 31) * (T_ * IN_) + (n >> 5) * IN_ + kq * 4;

    const int tm = (tid >> 4) * 4;
    const int tn = (tid & 15) * 4;

    float c[4][4] = {};

    for (int k0 = 0; k0 < IN_; k0 += 16) {
        float4 av = *(const float4*)(aSrc + k0);
        float4 bv = *(const float4*)(bSrc + k0);
        __syncthreads();
        As[kq * 4 + 0][row] = av.x; As[kq * 4 + 1][row] = av.y;
        As[kq * 4 + 2][row] = av.z; As[kq * 4 + 3][row] = av.w;
        Bs[kq * 4 + 0][row] = bv.x; Bs[kq * 4 + 1][row] = bv.y;
        Bs[kq * 4 + 2][row] = bv.z; Bs[kq * 4 + 3][row] = bv.w;
        __syncthreads();
#pragma unroll
        for (int k = 0; k < 16; ++k) {
            float4 a = *(const float4*)&As[k][tm];
            float4 b = *(const float4*)&Bs[k][tn];
            c[0][0] += a.x * b.x; c[0][1] += a.x * b.y; c[0][2] += a.x * b.z; c[0][3] += a.x * b.w;
            c[1][0] += a.y * b.x; c[1][1] += a.y * b.y; c[1][2] += a.y * b.z; c[1][3] += a.y * b.w;
            c[2][0] += a.z * b.x; c[2][1] += a.z * b.y; c[2][2] += a.z * b.z; c[2][3] += a.z * b.w;
            c[3][0] += a.w * b.x; c[3][1] += a.w * b.y; c[3][2] += a.w * b.z; c[3][3] += a.w * b.w;
        }
    }

    const int nn = n0 + tn;
    const int tbase = nn >> 5;
    const int bb = nn & 31;
#pragma unroll
    for (int mi = 0; mi < 4; ++mi) {
        float4 v = make_float4(c[mi][0], c[mi][1], c[mi][2], c[mi][3]);
        *(float4*)(xe + tbase * HB_ + (m0 + tm + mi) * B_ + bb) = v;
    }
}

// ---------------------------------------------------------------------------
// Persistent cooperative scan. 1024 blocks x 256 threads, 65 skewed phases:
//   phase t: A-blocks (0..511)  : h0(t)   = relu(xe[t] + S0 @ h0(t-1))   [t<64]
//            B-blocks (512..1023): h1(t-1) = relu(S1 @ hsum_rd)          [t>=1]
//   both producers atomicAdd into hsum_wr = h0(t) + h1(t-1) for phase t+1.
// h_final: register-direct stores (A at t=63 -> layer 0; B at t=64 -> layer 1).
// ---------------------------------------------------------------------------
__global__ __launch_bounds__(256) void scan_kernel(
    const int*   __restrict__ hh_idx, const float* __restrict__ hh_vals,
    const float* __restrict__ xe, float* __restrict__ h0buf,
    float* __restrict__ hsum, float* __restrict__ out) {
    cg::grid_group grid = cg::this_grid();
    __shared__ int2  tab[512];    // 8 rows x 64 nnz: {idx*B_, bits(val)}
    __shared__ float ldsT[256];   // 8x32 output transpose staging (B role)

    const int bid = blockIdx.x, tid = threadIdx.x;
    const int roleB = bid >= 512;
    const int rb = (bid & 511) * 8;          // this block's row base
    const int gtid = bid * NTHR + tid;

    {   // preload this block's sparse rows (once for all 65 phases)
        const int*   ip = hh_idx  + roleB * (H_ * K_) + rb * K_;
        const float* vp = hh_vals + roleB * (H_ * K_) + rb * K_;
        for (int e = tid; e < 512; e += NTHR)
            tab[e] = make_int2(ip[e] * B_, __float_as_int(vp[e]));
    }
    // zero hsum[1] (accumulation target of phase 0); hsum[0] is never read
    if (gtid < HB_) hsum[HB_ + gtid] = 0.f;
    grid.sync();

    const int wid = tid >> 6, lane = tid & 63;
    const int kh = lane >> 5, b = lane & 31;  // lanes = (k-half) x (batch)

    for (int t = 0; t <= T_; ++t) {
        const float* h0_rd = h0buf + ((t + 1) & 1) * HB_;   // h0(t-1)
        float*       h0_wr = h0buf + (t & 1) * HB_;         // h0(t)
        const float* hs_rd = hsum + (t % 3) * HB_;          // h0(t-1)+h1(t-2)
        float*       hs_wr = hsum + ((t + 1) % 3) * HB_;    // accumulating
        float*       hs_zr = hsum + ((t + 2) % 3) * HB_;    // zero for t+1

        if (t < 63 && gtid < HB_) hs_zr[gtid] = 0.f;

        if (!roleB) {                        // ---- layer 0 ----
            if (t < T_) {
                const float* xe_t = xe + t * HB_;
#pragma unroll
                for (int rep = 0; rep < 2; ++rep) {
                    const int rl = wid * 2 + rep, h = rb + rl;
                    float acc = 0.f;
                    if (t > 0) {
                        const int2* tp = tab + rl * 64 + kh * 32;
#pragma unroll
                        for (int k2 = 0; k2 < 32; ++k2) {
                            int2 p = tp[k2];
                            acc += __int_as_float(p.y) * h0_rd[p.x + b];
                        }
                    }
                    acc += __shfl_xor(acc, 32);
                    acc += xe_t[h * B_ + b];
                    acc = fmaxf(acc, 0.f);
                    if (kh == 0) {
                        h0_wr[h * B_ + b] = acc;
                        atomicAdd(&hs_wr[h * B_ + b], acc);
                        if (t == T_ - 1)               // h_final layer 0, from register
                            out[OFF0 + b * H_ + h] = acc;
                    }
                }
            }
            // t == T_: idle phase (B still computing h1(63))
        } else if (t >= 1) {                 // ---- layer 1 ----
            const int s = t - 1;
#pragma unroll
            for (int rep = 0; rep < 2; ++rep) {
                const int rl = wid * 2 + rep, h = rb + rl;
                const int2* tp = tab + rl * 64 + kh * 32;
                float acc = 0.f;
#pragma unroll
                for (int k2 = 0; k2 < 32; ++k2) {
                    int2 p = tp[k2];
                    acc += __int_as_float(p.y) * hs_rd[p.x + b];
                }
                acc += __shfl_xor(acc, 32);
                acc = fmaxf(acc, 0.f);
                if (kh == 0) {
                    if (t < T_) atomicAdd(&hs_wr[h * B_ + b], acc);
                    else        out[OFF1 + b * H_ + h] = acc;  // h_final layer 1, from register
                    ldsT[rl * 32 + b] = acc;
                }
            }
            __syncthreads();
            // coalesce out[b][s][h]: 8 consecutive h per 8-thread group
            const int b_o = tid >> 3, hl = tid & 7;
            out[b_o * (T_ * H_) + s * H_ + rb + hl] = ldsT[hl * 32 + b_o];
        }
        grid.sync();
    }
}

extern "C" void kernel_launch(void* const* d_in, const int* in_sizes, int n_in,
                              void* d_out, int out_size, void* d_ws, size_t ws_size,
                              hipStream_t stream) {
    const float* x       = (const float*)d_in[0];
    const float* w_ih    = (const float*)d_in[1];
    const int*   hh_idx  = (const int*)d_in[2];
    const float* hh_vals = (const float*)d_in[3];
    float* out = (float*)d_out;
    float* ws  = (float*)d_ws;

    float* xe    = ws;                    // [T][H][B]
    float* h0buf = ws + XE_ELEMS;         // [2][H][B]
    float* hsum  = h0buf + 2 * HB_;       // [3][H][B]

    gemm_xe<<<dim3(64, 32), 256, 0, stream>>>(x, w_ih, xe);

    void* args[] = {(void*)&hh_idx, (void*)&hh_vals, (void*)&xe,
                    (void*)&h0buf, (void*)&hsum, (void*)&out};
    hipLaunchCooperativeKernel((const void*)scan_kernel, dim3(NBLK), dim3(NTHR),
                               args, 0, stream);
}

// Round 15
// 4450.127 us; speedup vs baseline: 2.0147x; 2.0147x over previous
//
#include <hip/hip_runtime.h>

// BalRNN: B=32, T=64, IN=512, L=2, H=4096, K=64
// ws layout (floats):
//   xe    [T][H][B]   offset 0            (8,388,608)
//   h0    [2][H][B]   offset 8,388,608    (262,144)  double-buffered h0 state
//   hsum  [3][H][B]   offset 8,650,752    (393,216)  h0(t)+h1(t-1) accumulator
//   bar   [32][64]    offset 9,043,968    (2,048 ints) distributed barrier ctrs
// state layout [h][b]: one gathered row = 128B contiguous, 128B-aligned.
// h_final written REGISTER-DIRECT (R8-proven): A@t=63 -> L0, B@t=64 -> L1.
// R8 lesson: cg::grid.sync() = 136 us/phase (single system-scope counter,
// 1024 blocks serialized). Replaced with 32-counter monotonic barrier.

constexpr int B_ = 32, T_ = 64, IN_ = 512, H_ = 4096, K_ = 64;
constexpr int HB_ = H_ * B_;            // 131072
constexpr int XE_ELEMS = T_ * HB_;      // 8388608
constexpr int NBLK = 1024, NTHR = 256;
constexpr int OFF0 = B_ * T_ * H_;      // h_final layer-0 region in d_out
constexpr int OFF1 = OFF0 + B_ * H_;    // h_final layer-1 region in d_out

// ---------------------------------------------------------------------------
// xe[t][h][b] = sum_i w[h][i] * x[b][t][i]   (measured R1: 131 us)
// ---------------------------------------------------------------------------
__global__ __launch_bounds__(256) void gemm_xe(const float* __restrict__ x,
                                               const float* __restrict__ w,
                                               float* __restrict__ xe) {
    __shared__ float As[16][64];
    __shared__ float Bs[16][64];
    const int tid = threadIdx.x;
    const int m0 = blockIdx.x * 64;
    const int n0 = blockIdx.y * 64;
    const int row = tid >> 2;
    const int kq  = tid & 3;

    const float* aSrc = w + (m0 + row) * IN_ + kq * 4;
    const int n = n0 + row;
    const float* bSrc = x + (n & 31) * (T_ * IN_) + (n >> 5) * IN_ + kq * 4;

    const int tm = (tid >> 4) * 4;
    const int tn = (tid & 15) * 4;

    float c[4][4] = {};

    for (int k0 = 0; k0 < IN_; k0 += 16) {
        float4 av = *(const float4*)(aSrc + k0);
        float4 bv = *(const float4*)(bSrc + k0);
        __syncthreads();
        As[kq * 4 + 0][row] = av.x; As[kq * 4 + 1][row] = av.y;
        As[kq * 4 + 2][row] = av.z; As[kq * 4 + 3][row] = av.w;
        Bs[kq * 4 + 0][row] = bv.x; Bs[kq * 4 + 1][row] = bv.y;
        Bs[kq * 4 + 2][row] = bv.z; Bs[kq * 4 + 3][row] = bv.w;
        __syncthreads();
#pragma unroll
        for (int k = 0; k < 16; ++k) {
            float4 a = *(const float4*)&As[k][tm];
            float4 b = *(const float4*)&Bs[k][tn];
            c[0][0] += a.x * b.x; c[0][1] += a.x * b.y; c[0][2] += a.x * b.z; c[0][3] += a.x * b.w;
            c[1][0] += a.y * b.x; c[1][1] += a.y * b.y; c[1][2] += a.y * b.z; c[1][3] += a.y * b.w;
            c[2][0] += a.z * b.x; c[2][1] += a.z * b.y; c[2][2] += a.z * b.z; c[2][3] += a.z * b.w;
            c[3][0] += a.w * b.x; c[3][1] += a.w * b.y; c[3][2] += a.w * b.z; c[3][3] += a.w * b.w;
        }
    }

    const int nn = n0 + tn;
    const int tbase = nn >> 5;
    const int bb = nn & 31;
#pragma unroll
    for (int mi = 0; mi < 4; ++mi) {
        float4 v = make_float4(c[mi][0], c[mi][1], c[mi][2], c[mi][3]);
        *(float4*)(xe + tbase * HB_ + (m0 + tm + mi) * B_ + bb) = v;
    }
}

// ---------------------------------------------------------------------------
// Distributed grid barrier: 32 monotonic counters, 256B apart. Each block
// fetch_adds its counter (32-way parallel arrival); lanes 0..31 each poll one
// counter. __syncthreads drains the block's stores (vmcnt 0 before s_barrier);
// __threadfence release pushes L2->coherence point / acquire invalidates.
// ---------------------------------------------------------------------------
__device__ __forceinline__ void gbar(int* cnt, int target) {
    __syncthreads();
    if (threadIdx.x == 0) {
        __threadfence();                       // release
        __hip_atomic_fetch_add(&cnt[(blockIdx.x & 31) << 6], 1,
                               __ATOMIC_RELAXED, __HIP_MEMORY_SCOPE_AGENT);
    }
    if (threadIdx.x < 32) {
        while (__hip_atomic_load(&cnt[threadIdx.x << 6],
                                 __ATOMIC_RELAXED, __HIP_MEMORY_SCOPE_AGENT) < target) {}
    }
    __syncthreads();
    if (threadIdx.x == 0) __threadfence();     // acquire
    __syncthreads();
}

// ---------------------------------------------------------------------------
// Persistent cooperative scan. 1024 blocks x 256 threads, 65 skewed phases:
//   phase t: A-blocks (0..511)  : h0(t)   = relu(xe[t] + S0 @ h0(t-1))   [t<64]
//            B-blocks (512..1023): h1(t-1) = relu(S1 @ hsum_rd)          [t>=1]
//   both producers atomicAdd into hsum_wr = h0(t) + h1(t-1) for phase t+1.
// h_final: register-direct stores (A at t=63 -> layer 0; B at t=64 -> layer 1).
// ---------------------------------------------------------------------------
__global__ __launch_bounds__(256) void scan_kernel(
    const int*   __restrict__ hh_idx, const float* __restrict__ hh_vals,
    const float* __restrict__ xe, float* __restrict__ h0buf,
    float* __restrict__ hsum, float* __restrict__ out, int* bar) {
    __shared__ int2  tab[512];    // 8 rows x 64 nnz: {idx*B_, bits(val)}
    __shared__ float ldsT[256];   // 8x32 output transpose staging (B role)

    const int bid = blockIdx.x, tid = threadIdx.x;
    const int roleB = bid >= 512;
    const int rb = (bid & 511) * 8;          // this block's row base
    const int gtid = bid * NTHR + tid;

    {   // preload this block's sparse rows (once for all 65 phases)
        const int*   ip = hh_idx  + roleB * (H_ * K_) + rb * K_;
        const float* vp = hh_vals + roleB * (H_ * K_) + rb * K_;
        for (int e = tid; e < 512; e += NTHR)
            tab[e] = make_int2(ip[e] * B_, __float_as_int(vp[e]));
    }
    // zero hsum[1] (accumulation target of phase 0); hsum[0] is never read
    if (gtid < HB_) hsum[HB_ + gtid] = 0.f;

    int tgt = 32;                 // 32 blocks per counter arrive per barrier
    gbar(bar, tgt); tgt += 32;

    const int wid = tid >> 6, lane = tid & 63;
    const int kh = lane >> 5, b = lane & 31;  // lanes = (k-half) x (batch)

    for (int t = 0; t <= T_; ++t) {
        const float* h0_rd = h0buf + ((t + 1) & 1) * HB_;   // h0(t-1)
        float*       h0_wr = h0buf + (t & 1) * HB_;         // h0(t)
        const float* hs_rd = hsum + (t % 3) * HB_;          // h0(t-1)+h1(t-2)
        float*       hs_wr = hsum + ((t + 1) % 3) * HB_;    // accumulating
        float*       hs_zr = hsum + ((t + 2) % 3) * HB_;    // zero for t+1

        if (t < 63 && gtid < HB_) hs_zr[gtid] = 0.f;

        if (!roleB) {                        // ---- layer 0 ----
            if (t < T_) {
                const float* xe_t = xe + t * HB_;
#pragma unroll
                for (int rep = 0; rep < 2; ++rep) {
                    const int rl = wid * 2 + rep, h = rb + rl;
                    float acc = 0.f;
                    if (t > 0) {
                        const int2* tp = tab + rl * 64 + kh * 32;
#pragma unroll
                        for (int k2 = 0; k2 < 32; ++k2) {
                            int2 p = tp[k2];
                            acc += __int_as_float(p.y) * h0_rd[p.x + b];
                        }
                    }
                    acc += __shfl_xor(acc, 32);
                    acc += xe_t[h * B_ + b];
                    acc = fmaxf(acc, 0.f);
                    if (kh == 0) {
                        h0_wr[h * B_ + b] = acc;
                        atomicAdd(&hs_wr[h * B_ + b], acc);
                        if (t == T_ - 1)               // h_final layer 0, from register
                            out[OFF0 + b * H_ + h] = acc;
                    }
                }
            }
            // t == T_: idle phase (B still computing h1(63))
        } else if (t >= 1) {                 // ---- layer 1 ----
            const int s = t - 1;
#pragma unroll
            for (int rep = 0; rep < 2; ++rep) {
                const int rl = wid * 2 + rep, h = rb + rl;
                const int2* tp = tab + rl * 64 + kh * 32;
                float acc = 0.f;
#pragma unroll
                for (int k2 = 0; k2 < 32; ++k2) {
                    int2 p = tp[k2];
                    acc += __int_as_float(p.y) * hs_rd[p.x + b];
                }
                acc += __shfl_xor(acc, 32);
                acc = fmaxf(acc, 0.f);
                if (kh == 0) {
                    if (t < T_) atomicAdd(&hs_wr[h * B_ + b], acc);
                    else        out[OFF1 + b * H_ + h] = acc;  // h_final layer 1, from register
                    ldsT[rl * 32 + b] = acc;
                }
            }
            __syncthreads();
            // coalesce out[b][s][h]: 8 consecutive h per 8-thread group
            const int b_o = tid >> 3, hl = tid & 7;
            out[b_o * (T_ * H_) + s * H_ + rb + hl] = ldsT[hl * 32 + b_o];
        }
        gbar(bar, tgt); tgt += 32;
    }
}

extern "C" void kernel_launch(void* const* d_in, const int* in_sizes, int n_in,
                              void* d_out, int out_size, void* d_ws, size_t ws_size,
                              hipStream_t stream) {
    const float* x       = (const float*)d_in[0];
    const float* w_ih    = (const float*)d_in[1];
    const int*   hh_idx  = (const int*)d_in[2];
    const float* hh_vals = (const float*)d_in[3];
    float* out = (float*)d_out;
    float* ws  = (float*)d_ws;

    float* xe    = ws;                    // [T][H][B]
    float* h0buf = ws + XE_ELEMS;         // [2][H][B]
    float* hsum  = h0buf + 2 * HB_;       // [3][H][B]
    int*   bar   = (int*)(hsum + 3 * HB_);// [32][64] counters

    hipMemsetAsync(bar, 0, 32 * 64 * sizeof(int), stream);

    gemm_xe<<<dim3(64, 32), 256, 0, stream>>>(x, w_ih, xe);

    void* args[] = {(void*)&hh_idx, (void*)&hh_vals, (void*)&xe,
                    (void*)&h0buf, (void*)&hsum, (void*)&out, (void*)&bar};
    hipLaunchCooperativeKernel((const void*)scan_kernel, dim3(NBLK), dim3(NTHR),
                               args, 0, stream);
}